// Round 9
// baseline (1381.527 us; speedup 1.0000x reference)
//
#include <hip/hip_runtime.h>
#include <hip/hip_bf16.h>
#include <cstdint>
#include <cstddef>

// ---------------------------------------------------------------------------
// RNNAttentionModel megakernel: 4 producer blocks run the MFMA RNN scan;
// 220 consumer blocks run fused (qproj + flash attention + FC) per (qt,b)
// item, gated on cross-XCD progress flags (device-scope atomics).
// B=64 T=1024 E=64 H=128 V=55
// ---------------------------------------------------------------------------

typedef __attribute__((ext_vector_type(8))) short short8;
typedef __attribute__((ext_vector_type(4))) float f32x4;

#define NCONS 220

__device__ __forceinline__ float bf2f(unsigned short u) {
    union { unsigned int i; float f; } c; c.i = ((unsigned int)u) << 16; return c.f;
}
__device__ __forceinline__ unsigned short f2bf(float f) {
    union { float f; unsigned int i; } c; c.f = f;
    unsigned int u = c.i;
    u += 0x7fffu + ((u >> 16) & 1u);   // RNE
    return (unsigned short)(u >> 16);
}
__device__ __forceinline__ unsigned int pk_bf16(float lo, float hi) {
    union { __hip_bfloat162 h2; unsigned int u; } c;
    c.h2 = __float22bfloat162_rn(make_float2(lo, hi));
    return c.u;
}
__device__ __forceinline__ float fast_tanh(float x) {
    float e = __expf(2.0f * x);
    return 1.0f - 2.0f * __builtin_amdgcn_rcpf(e + 1.0f);
}
__device__ __forceinline__ void bar_lds() {
    asm volatile("s_waitcnt lgkmcnt(0)\n\ts_barrier" ::: "memory");
}
__device__ __forceinline__ short8 ld_a_bf16(const float* p) {
    const float4* q = (const float4*)p;
    float4 f0 = q[0], f1 = q[1];
    short8 r;
    r[0]=(short)f2bf(f0.x); r[1]=(short)f2bf(f0.y);
    r[2]=(short)f2bf(f0.z); r[3]=(short)f2bf(f0.w);
    r[4]=(short)f2bf(f1.x); r[5]=(short)f2bf(f1.y);
    r[6]=(short)f2bf(f1.z); r[7]=(short)f2bf(f1.w);
    return r;
}
// split-precision load: hi = bf16(w), lo = bf16(w - hi); hi+lo ~ f32 weight
__device__ __forceinline__ void ld_fc_hilo(const float* p, short8& hi, short8& lo) {
    const float4* q = (const float4*)p;
    float4 f0 = q[0], f1 = q[1];
    float ff[8] = {f0.x, f0.y, f0.z, f0.w, f1.x, f1.y, f1.z, f1.w};
#pragma unroll
    for (int i = 0; i < 8; ++i) {
        unsigned short hb = f2bf(ff[i]);
        hi[i] = (short)hb;
        lo[i] = (short)f2bf(ff[i] - bf2f(hb));
    }
}

// ---------------------------------------------------------------------------
// K0a: WE[v][i] = w_ih0[i,:].emb[v,:] + b_ih0[i] + b_hh0[i]; zero progress
// ---------------------------------------------------------------------------
__global__ __launch_bounds__(128)
void k_we(const float* __restrict__ emb, const float* __restrict__ w_ih0,
          const float* __restrict__ b_ih0, const float* __restrict__ b_hh0,
          float* __restrict__ WE, int* __restrict__ progress)
{
    __shared__ float ev[64];
    const int i = threadIdx.x;
    const int v = blockIdx.x;
    if (v == 0 && i < 4) progress[i] = 0;
    if (i < 64) ev[i] = emb[v * 64 + i];
    __syncthreads();
    float s = b_ih0[i] + b_hh0[i];
    const float* wr = w_ih0 + i * 64;
#pragma unroll
    for (int k = 0; k < 64; ++k) s += wr[k] * ev[k];
    WE[v * 128 + i] = s;
}

// ---------------------------------------------------------------------------
// K0b: WEg[b][t][:] = WE[x[b][t]][:]
// ---------------------------------------------------------------------------
__global__ __launch_bounds__(256)
void k_weg(const int* __restrict__ x, const float* __restrict__ WE,
           float* __restrict__ WEg)
{
    __shared__ int xv[32];
    const int tid = threadIdx.x;
    const int b   = blockIdx.y;
    const int t0  = blockIdx.x * 32;
    if (tid < 32) xv[tid] = x[b * 1024 + t0 + tid];
    __syncthreads();
#pragma unroll
    for (int it = 0; it < 4; ++it) {
        int tt = it * 8 + (tid >> 5);
        int c4 = tid & 31;
        float4 v = ((const float4*)(WE + xv[tt] * 128))[c4];
        ((float4*)(WEg + ((size_t)b * 1024 + t0 + tt) * 128))[c4] = v;
    }
}

// ---------------------------------------------------------------------------
// Megakernel
// ---------------------------------------------------------------------------
__global__ __launch_bounds__(512, 2)
void k_mega(const float* __restrict__ WEg,
            const float* __restrict__ w_hh0,
            const float* __restrict__ w_ih1, const float* __restrict__ b_ih1,
            const float* __restrict__ w_hh1, const float* __restrict__ b_hh1,
            unsigned short* __restrict__ outs_bf,
            const float* __restrict__ attn_w, const float* __restrict__ attn_b,
            const float* __restrict__ fc_w, const float* __restrict__ fc_b,
            float* __restrict__ out, int* __restrict__ progress)
{
    // shared overlay: producer uses [0,17408); consumer uses [0,100352)
    __shared__ __align__(16) unsigned char smem[100352];

    const int tid  = threadIdx.x;
    const int w    = tid >> 6;
    const int lane = tid & 63;
    const int quad = lane >> 4;
    const int n    = lane & 15;

    if (blockIdx.x < 4) {
        // =================== PRODUCER: RNN scan (k_scan5) ==================
        typedef unsigned short (*hb_t)[16][136];
        hb_t h0buf = (hb_t)smem;              // [2][16][136]
        hb_t h1buf = (hb_t)(smem + 8704);
        const int g     = blockIdx.x;
        const int bbase = g * 16;

        if (w < 4) {
            // ---- A-waves: layer 0, M-tiles 2w, 2w+1 ----
            const int r0 = w * 32 + quad * 4;
            const int r1 = r0 + 16;
            short8 a0[2][4];
#pragma unroll
            for (int r = 0; r < 2; ++r) {
                const size_t mrow = (size_t)(w * 32 + r * 16 + n) * 128;
#pragma unroll
                for (int ks = 0; ks < 4; ++ks)
                    a0[r][ks] = ld_a_bf16(w_hh0 + mrow + ks * 32 + quad * 8);
            }
            const size_t wegB0 = (size_t)(bbase + n) * 131072 + r0;
            const size_t wegB1 = wegB0 + 16;
            {
                float4 p0 = *(const float4*)(WEg + wegB0);
                float4 p1 = *(const float4*)(WEg + wegB1);
                *(uint2*)&h0buf[0][n][r0] = make_uint2(
                    pk_bf16(fast_tanh(p0.x), fast_tanh(p0.y)),
                    pk_bf16(fast_tanh(p0.z), fast_tanh(p0.w)));
                *(uint2*)&h0buf[0][n][r1] = make_uint2(
                    pk_bf16(fast_tanh(p1.x), fast_tanh(p1.y)),
                    pk_bf16(fast_tanh(p1.z), fast_tanh(p1.w)));
            }
            float4 wA0 = *(const float4*)(WEg + wegB0 + 128);
            float4 wA1 = *(const float4*)(WEg + wegB1 + 128);
            float4 wB0 = *(const float4*)(WEg + wegB0 + 256);
            float4 wB1 = *(const float4*)(WEg + wegB1 + 256);
            float4 wC0 = *(const float4*)(WEg + wegB0 + 384);
            float4 wC1 = *(const float4*)(WEg + wegB1 + 384);
            __syncthreads();

            for (int t = 0; t < 1024; ++t) {
                const int p = t & 1;
                if (t < 1023) {
                    const unsigned short* h0p = &h0buf[p][n][quad * 8];
                    short8 bh[4];
#pragma unroll
                    for (int ks = 0; ks < 4; ++ks)
                        bh[ks] = *(const short8*)(h0p + ks * 32);
                    f32x4 c0 = (f32x4){wA0.x, wA0.y, wA0.z, wA0.w};
                    f32x4 c1 = (f32x4){wA1.x, wA1.y, wA1.z, wA1.w};
#pragma unroll
                    for (int ks = 0; ks < 4; ++ks) {
                        c0 = __builtin_amdgcn_mfma_f32_16x16x32_bf16(a0[0][ks], bh[ks], c0, 0,0,0);
                        c1 = __builtin_amdgcn_mfma_f32_16x16x32_bf16(a0[1][ks], bh[ks], c1, 0,0,0);
                    }
                    wA0 = wB0; wA1 = wB1; wB0 = wC0; wB1 = wC1;
                    const size_t tpre = (size_t)((t + 4 < 1024) ? t + 4 : 1023) * 128;
                    wC0 = *(const float4*)(WEg + wegB0 + tpre);
                    wC1 = *(const float4*)(WEg + wegB1 + tpre);
                    *(uint2*)&h0buf[p ^ 1][n][r0] = make_uint2(
                        pk_bf16(fast_tanh(c0[0]), fast_tanh(c0[1])),
                        pk_bf16(fast_tanh(c0[2]), fast_tanh(c0[3])));
                    *(uint2*)&h0buf[p ^ 1][n][r1] = make_uint2(
                        pk_bf16(fast_tanh(c1[0]), fast_tanh(c1[1])),
                        pk_bf16(fast_tanh(c1[2]), fast_tanh(c1[3])));
                }
                if ((t & 127) == 127) {
                    __syncthreads();           // drains each wave's vmcnt
                    if (tid == 0) {
                        __hip_atomic_store(progress + g, t + 1,
                                           __ATOMIC_RELEASE,
                                           __HIP_MEMORY_SCOPE_AGENT);
                    }
                } else {
                    bar_lds();
                }
            }
        } else {
            // ---- B-waves: layer 1, M-tiles 2w', 2w'+1 ----
            const int w2 = w - 4;
            const int r0 = w2 * 32 + quad * 4;
            const int r1 = r0 + 16;
            short8 a1[2][4], a2[2][4];
#pragma unroll
            for (int r = 0; r < 2; ++r) {
                const size_t mrow = (size_t)(w2 * 32 + r * 16 + n) * 128;
#pragma unroll
                for (int ks = 0; ks < 4; ++ks) {
                    a1[r][ks] = ld_a_bf16(w_ih1 + mrow + ks * 32 + quad * 8);
                    a2[r][ks] = ld_a_bf16(w_hh1 + mrow + ks * 32 + quad * 8);
                }
            }
            f32x4 b1i[2];
#pragma unroll
            for (int r = 0; r < 2; ++r)
#pragma unroll
                for (int j = 0; j < 4; ++j) {
                    int row = w2 * 32 + r * 16 + quad * 4 + j;
                    b1i[r][j] = b_ih1[row] + b_hh1[row];
                }
            *(uint2*)&h1buf[0][n][r0] = make_uint2(0u, 0u);
            *(uint2*)&h1buf[0][n][r1] = make_uint2(0u, 0u);
            unsigned short* outp0 = outs_bf + (size_t)(bbase + n) * 131072 + r0;
            unsigned short* outp1 = outp0 + 16;
            __syncthreads();

            for (int t = 0; t < 1024; ++t) {
                const int p = t & 1;
                const unsigned short* h0p = &h0buf[p][n][quad * 8];
                const unsigned short* h1p = &h1buf[p][n][quad * 8];
                short8 bh0[4], bh1[4];
#pragma unroll
                for (int ks = 0; ks < 4; ++ks) {
                    bh0[ks] = *(const short8*)(h0p + ks * 32);
                    bh1[ks] = *(const short8*)(h1p + ks * 32);
                }
                f32x4 c0 = b1i[0], c1 = b1i[1];
                f32x4 d0 = (f32x4){0.f,0.f,0.f,0.f}, d1 = (f32x4){0.f,0.f,0.f,0.f};
#pragma unroll
                for (int ks = 0; ks < 4; ++ks) {
                    c0 = __builtin_amdgcn_mfma_f32_16x16x32_bf16(a1[0][ks], bh0[ks], c0, 0,0,0);
                    c1 = __builtin_amdgcn_mfma_f32_16x16x32_bf16(a1[1][ks], bh0[ks], c1, 0,0,0);
                    d0 = __builtin_amdgcn_mfma_f32_16x16x32_bf16(a2[0][ks], bh1[ks], d0, 0,0,0);
                    d1 = __builtin_amdgcn_mfma_f32_16x16x32_bf16(a2[1][ks], bh1[ks], d1, 0,0,0);
                }
                uint2 o0 = make_uint2(
                    pk_bf16(fast_tanh(c0[0] + d0[0]), fast_tanh(c0[1] + d0[1])),
                    pk_bf16(fast_tanh(c0[2] + d0[2]), fast_tanh(c0[3] + d0[3])));
                uint2 o1 = make_uint2(
                    pk_bf16(fast_tanh(c1[0] + d1[0]), fast_tanh(c1[1] + d1[1])),
                    pk_bf16(fast_tanh(c1[2] + d1[2]), fast_tanh(c1[3] + d1[3])));
                *(uint2*)&h1buf[p ^ 1][n][r0] = o0;
                *(uint2*)&h1buf[p ^ 1][n][r1] = o1;
                *(uint2*)(outp0 + (size_t)t * 128) = o0;
                *(uint2*)(outp1 + (size_t)t * 128) = o1;
                if ((t & 127) == 127) __syncthreads();
                else                  bar_lds();
            }
        }
        return;
    }

    // ======================= CONSUMER: attention + FC ======================
    unsigned short* lK = (unsigned short*)smem;             // [128][128] swz
    unsigned short* lV = (unsigned short*)(smem + 32768);   // [128][128] swz (V^T)
    unsigned short* lP = (unsigned short*)(smem + 65536);   // [8][16][136]
    unsigned short* lPw = lP + w * 2176;
    const int cid = (int)blockIdx.x - 4;
    const float cscale = 0.08838834764831845f;              // 1/sqrt(128)

    for (int j = cid; j < 512; j += NCONS) {
        const int qt = j >> 6;
        const int b  = j & 63;
        if (tid == 0) {
            while (__hip_atomic_load(progress + (b >> 4), __ATOMIC_ACQUIRE,
                                     __HIP_MEMORY_SCOPE_AGENT) < (qt + 1) * 128)
                __builtin_amdgcn_s_sleep(32);
        }
        __syncthreads();
        __threadfence();   // invalidate stale cached outs lines for all threads

        const unsigned short* outsB = outs_bf + (size_t)b * 131072;
        const int qrow = qt * 128 + w * 16 + n;             // this lane's q

        // ---- Phase Q: Q = attn_w @ outs_q + attn_b (per-wave 16 rows) ----
        short8 bo[4];
#pragma unroll
        for (int ks = 0; ks < 4; ++ks)
            bo[ks] = *(const short8*)(outsB + (size_t)qrow * 128 + ks * 32 + quad * 8);
#pragma unroll
        for (int mt = 0; mt < 8; ++mt) {
            short8 aw[4];
#pragma unroll
            for (int ks = 0; ks < 4; ++ks)
                aw[ks] = ld_a_bf16(attn_w + (size_t)(mt * 16 + n) * 128 + ks * 32 + quad * 8);
            f32x4 cq;
#pragma unroll
            for (int r = 0; r < 4; ++r) cq[r] = attn_b[mt * 16 + quad * 4 + r];
#pragma unroll
            for (int ks = 0; ks < 4; ++ks)
                cq = __builtin_amdgcn_mfma_f32_16x16x32_bf16(aw[ks], bo[ks], cq, 0,0,0);
            *(uint2*)&lPw[n * 136 + mt * 16 + quad * 4] =
                make_uint2(pk_bf16(cq[0], cq[1]), pk_bf16(cq[2], cq[3]));
        }
        short8 qf[4];
#pragma unroll
        for (int ks = 0; ks < 4; ++ks)
            qf[ks] = *(const short8*)&lPw[n * 136 + ks * 32 + quad * 8];

        f32x4 accO[8];
#pragma unroll
        for (int dt = 0; dt < 8; ++dt) accO[dt] = (f32x4){0.f, 0.f, 0.f, 0.f};
        float mx = -1e30f, lsum = 0.f;

        for (int kt = 0; kt <= qt; ++kt) {
            __syncthreads();                   // previous iter done with lK/lV
            for (int c = tid; c < 2048; c += 512) {
                int row = c >> 4, k8 = c & 15;
                uint4 v4 = *(const uint4*)(outsB + (size_t)(kt * 128 + row) * 128 + k8 * 8);
                *(uint4*)&lK[row * 128 + ((k8 ^ (row & 15)) << 3)] = v4;
                const unsigned short* pv = (const unsigned short*)&v4;
#pragma unroll
                for (int jj = 0; jj < 8; ++jj) {
                    int d = k8 * 8 + jj;
                    lV[d * 128 + (((row >> 3) ^ (d & 15)) << 3) + (row & 7)] = pv[jj];
                }
            }
            __syncthreads();
            // ---- S^T = K · Q^T ----
            f32x4 accS[8];
#pragma unroll
            for (int mt = 0; mt < 8; ++mt) {
                short8 af[4];
#pragma unroll
                for (int ks = 0; ks < 4; ++ks) {
                    int r = mt * 16 + n;
                    af[ks] = *(const short8*)&lK[r * 128 + (((ks * 4 + quad) ^ (r & 15)) << 3)];
                }
                f32x4 s = (f32x4){0.f, 0.f, 0.f, 0.f};
#pragma unroll
                for (int ks = 0; ks < 4; ++ks)
                    s = __builtin_amdgcn_mfma_f32_16x16x32_bf16(af[ks], qf[ks], s, 0,0,0);
                accS[mt] = s;
            }
            if (kt == qt) {
                const int ql = w * 16 + n;
#pragma unroll
                for (int mt = 0; mt < 8; ++mt)
#pragma unroll
                    for (int jv = 0; jv < 4; ++jv)
                        if (mt * 16 + quad * 4 + jv > ql) accS[mt][jv] = -1e30f;
            }
            // ---- online softmax ----
            float tmax = accS[0][0];
#pragma unroll
            for (int mt = 0; mt < 8; ++mt)
#pragma unroll
                for (int jv = 0; jv < 4; ++jv) tmax = fmaxf(tmax, accS[mt][jv]);
            tmax = fmaxf(tmax, __shfl_xor(tmax, 16));
            tmax = fmaxf(tmax, __shfl_xor(tmax, 32));
            float nm = fmaxf(mx, tmax);
            float alpha = __expf((mx - nm) * cscale);
            float ss = 0.f;
#pragma unroll
            for (int mt = 0; mt < 8; ++mt)
#pragma unroll
                for (int jv = 0; jv < 4; ++jv) {
                    float p = __expf((accS[mt][jv] - nm) * cscale);
                    accS[mt][jv] = p;
                    ss += p;
                }
            ss += __shfl_xor(ss, 16);
            ss += __shfl_xor(ss, 32);
            lsum = lsum * alpha + ss;
            mx = nm;
            // ---- P^T -> wave-private LDS ----
#pragma unroll
            for (int mt = 0; mt < 8; ++mt)
                *(uint2*)&lPw[n * 136 + mt * 16 + quad * 4] = make_uint2(
                    pk_bf16(accS[mt][0], accS[mt][1]),
                    pk_bf16(accS[mt][2], accS[mt][3]));
#pragma unroll
            for (int dt = 0; dt < 8; ++dt)
#pragma unroll
                for (int jv = 0; jv < 4; ++jv) accO[dt][jv] *= alpha;
            short8 pf[4];
#pragma unroll
            for (int ks = 0; ks < 4; ++ks)
                pf[ks] = *(const short8*)&lPw[n * 136 + ks * 32 + quad * 8];
            // ---- O^T += V^T · P^T ----
#pragma unroll
            for (int dt = 0; dt < 8; ++dt) {
                short8 vf[4];
#pragma unroll
                for (int ks = 0; ks < 4; ++ks) {
                    int d = dt * 16 + n;
                    vf[ks] = *(const short8*)&lV[d * 128 + (((ks * 4 + quad) ^ (d & 15)) << 3)];
                }
#pragma unroll
                for (int ks = 0; ks < 4; ++ks)
                    accO[dt] = __builtin_amdgcn_mfma_f32_16x16x32_bf16(vf[ks], pf[ks], accO[dt], 0,0,0);
            }
        }
        // ---- epilogue: ctx (bf16) -> wave-private LDS ----
        {
            float inv = __builtin_amdgcn_rcpf(lsum);
#pragma unroll
            for (int dt = 0; dt < 8; ++dt)
                *(uint2*)&lPw[n * 136 + dt * 16 + quad * 4] = make_uint2(
                    pk_bf16(accO[dt][0] * inv, accO[dt][1] * inv),
                    pk_bf16(accO[dt][2] * inv, accO[dt][3] * inv));
        }
        // ---- inline FC: logits = [outs|ctx] @ fc_w.T + fc_b ----
        short8 bC[4];
#pragma unroll
        for (int ks = 0; ks < 4; ++ks)
            bC[ks] = *(const short8*)&lPw[n * 136 + ks * 32 + quad * 8];
#pragma unroll
        for (int mt = 0; mt < 4; ++mt) {
            const int vrow = mt * 16 + n;              // A-operand row (v)
            f32x4 acc;
#pragma unroll
            for (int r = 0; r < 4; ++r) {
                int vv = mt * 16 + quad * 4 + r;
                acc[r] = (vv < 55) ? fc_b[vv] : 0.f;
            }
#pragma unroll
            for (int c = 0; c < 8; ++c) {
                short8 hi, lo;
                if (vrow < 55) {
                    ld_fc_hilo(fc_w + (size_t)vrow * 256 + c * 32 + quad * 8, hi, lo);
                } else {
#pragma unroll
                    for (int i = 0; i < 8; ++i) { hi[i] = 0; lo[i] = 0; }
                }
                short8 bb = (c < 4) ? bo[c] : bC[c - 4];
                acc = __builtin_amdgcn_mfma_f32_16x16x32_bf16(hi, bb, acc, 0,0,0);
                acc = __builtin_amdgcn_mfma_f32_16x16x32_bf16(lo, bb, acc, 0,0,0);
            }
#pragma unroll
            for (int r = 0; r < 4; ++r) {
                int vv = mt * 16 + quad * 4 + r;
                if (vv < 55)
                    out[((size_t)b * 1024 + qrow) * 55 + vv] = acc[r];
            }
        }
        __syncthreads();
    }
}

// ---------------------------------------------------------------------------
extern "C" void kernel_launch(void* const* d_in, const int* in_sizes, int n_in,
                              void* d_out, int out_size, void* d_ws, size_t ws_size,
                              hipStream_t stream)
{
    const int*   x      = (const int*)d_in[0];
    const float* emb    = (const float*)d_in[1];
    const float* w_ih0  = (const float*)d_in[2];
    const float* b_ih0  = (const float*)d_in[3];
    const float* w_hh0  = (const float*)d_in[4];
    const float* b_hh0  = (const float*)d_in[5];
    const float* w_ih1  = (const float*)d_in[6];
    const float* b_ih1  = (const float*)d_in[7];
    const float* w_hh1  = (const float*)d_in[8];
    const float* b_hh1  = (const float*)d_in[9];
    const float* attn_w = (const float*)d_in[10];
    const float* attn_b = (const float*)d_in[11];
    const float* fc_w   = (const float*)d_in[12];
    const float* fc_b   = (const float*)d_in[13];
    float* out = (float*)d_out;

    char* ws = (char*)d_ws;
    unsigned short* outs_bf = (unsigned short*)(ws);                       // 16 MiB
    float*          WEp     = (float*)         (ws + ((size_t)16 << 20));  // 28 KiB
    float*          WEg     = (float*)         (ws + ((size_t)17 << 20));  // 32 MiB
    int*            prog    = (int*)           (ws + ((size_t)49 << 20));  // 16 B

    k_we<<<dim3(55), dim3(128), 0, stream>>>(emb, w_ih0, b_ih0, b_hh0, WEp, prog);
    k_weg<<<dim3(32, 64), dim3(256), 0, stream>>>(x, WEp, WEg);
    k_mega<<<dim3(4 + NCONS), dim3(512), 0, stream>>>(
        WEg, w_hh0, w_ih1, b_ih1, w_hh1, b_hh1, outs_bf,
        attn_w, attn_b, fc_w, fc_b, out, prog);
}

// Round 10
// 791.316 us; speedup vs baseline: 1.7459x; 1.7459x over previous
//
#include <hip/hip_runtime.h>
#include <hip/hip_bf16.h>
#include <cstdint>
#include <cstddef>

// ---------------------------------------------------------------------------
// RNNAttentionModel: embed -> 2-layer tanh RNN scan (MFMA-batched,
// wave-specialized) -> fused (qproj + flash attention + FC) -> out
// B=64 T=1024 E=64 H=128 V=55
// ---------------------------------------------------------------------------

typedef __attribute__((ext_vector_type(8))) short short8;
typedef __attribute__((ext_vector_type(4))) float f32x4;

__device__ __forceinline__ float bf2f(unsigned short u) {
    union { unsigned int i; float f; } c; c.i = ((unsigned int)u) << 16; return c.f;
}
__device__ __forceinline__ unsigned short f2bf(float f) {
    union { float f; unsigned int i; } c; c.f = f;
    unsigned int u = c.i;
    u += 0x7fffu + ((u >> 16) & 1u);   // RNE
    return (unsigned short)(u >> 16);
}
__device__ __forceinline__ unsigned int pk_bf16(float lo, float hi) {
    union { __hip_bfloat162 h2; unsigned int u; } c;
    c.h2 = __float22bfloat162_rn(make_float2(lo, hi));
    return c.u;
}
__device__ __forceinline__ float fast_tanh(float x) {
    float e = __expf(2.0f * x);
    return 1.0f - 2.0f * __builtin_amdgcn_rcpf(e + 1.0f);
}
__device__ __forceinline__ void bar_lds() {
    asm volatile("s_waitcnt lgkmcnt(0)\n\ts_barrier" ::: "memory");
}
__device__ __forceinline__ short8 ld_a_bf16(const float* p) {
    const float4* q = (const float4*)p;
    float4 f0 = q[0], f1 = q[1];
    short8 r;
    r[0]=(short)f2bf(f0.x); r[1]=(short)f2bf(f0.y);
    r[2]=(short)f2bf(f0.z); r[3]=(short)f2bf(f0.w);
    r[4]=(short)f2bf(f1.x); r[5]=(short)f2bf(f1.y);
    r[6]=(short)f2bf(f1.z); r[7]=(short)f2bf(f1.w);
    return r;
}
// split-precision load: hi = bf16(w), lo = bf16(w - hi); hi+lo ~ f32 weight
__device__ __forceinline__ void ld_fc_hilo(const float* p, short8& hi, short8& lo) {
    const float4* q = (const float4*)p;
    float4 f0 = q[0], f1 = q[1];
    float ff[8] = {f0.x, f0.y, f0.z, f0.w, f1.x, f1.y, f1.z, f1.w};
#pragma unroll
    for (int i = 0; i < 8; ++i) {
        unsigned short hb = f2bf(ff[i]);
        hi[i] = (short)hb;
        lo[i] = (short)f2bf(ff[i] - bf2f(hb));
    }
}

// ---------------------------------------------------------------------------
// K0a: WE[v][i] = w_ih0[i,:] . emb[v,:] + b_ih0[i] + b_hh0[i]   (55 x 128)
// ---------------------------------------------------------------------------
__global__ __launch_bounds__(128)
void k_we(const float* __restrict__ emb, const float* __restrict__ w_ih0,
          const float* __restrict__ b_ih0, const float* __restrict__ b_hh0,
          float* __restrict__ WE)
{
    __shared__ float ev[64];
    const int i = threadIdx.x;
    const int v = blockIdx.x;
    if (i < 64) ev[i] = emb[v * 64 + i];
    __syncthreads();
    float s = b_ih0[i] + b_hh0[i];
    const float* wr = w_ih0 + i * 64;
#pragma unroll
    for (int k = 0; k < 64; ++k) s += wr[k] * ev[k];
    WE[v * 128 + i] = s;
}

// ---------------------------------------------------------------------------
// K0b: WEg[b][t][:] = WE[x[b][t]][:]
// ---------------------------------------------------------------------------
__global__ __launch_bounds__(256)
void k_weg(const int* __restrict__ x, const float* __restrict__ WE,
           float* __restrict__ WEg)
{
    __shared__ int xv[32];
    const int tid = threadIdx.x;
    const int b   = blockIdx.y;
    const int t0  = blockIdx.x * 32;
    if (tid < 32) xv[tid] = x[b * 1024 + t0 + tid];
    __syncthreads();
#pragma unroll
    for (int it = 0; it < 4; ++it) {
        int tt = it * 8 + (tid >> 5);
        int c4 = tid & 31;
        float4 v = ((const float4*)(WE + xv[tt] * 128))[c4];
        ((float4*)(WEg + ((size_t)b * 1024 + t0 + tt) * 128))[c4] = v;
    }
}

// ---------------------------------------------------------------------------
// K1: MFMA-batched RNN scan, wave-specialized (unchanged from R5/R8).
// ---------------------------------------------------------------------------
__global__ __launch_bounds__(512, 1)
void k_scan5(const float* __restrict__ WEg,
             const float* __restrict__ w_hh0,
             const float* __restrict__ w_ih1, const float* __restrict__ b_ih1,
             const float* __restrict__ w_hh1, const float* __restrict__ b_hh1,
             unsigned short* __restrict__ outs_bf)
{
    const int tid   = threadIdx.x;
    const int w     = tid >> 6;          // 0..3 A-waves, 4..7 B-waves
    const int lane  = tid & 63;
    const int quad  = lane >> 4;
    const int n     = lane & 15;         // batch col
    const int bbase = blockIdx.x * 16;

    __shared__ __align__(16) unsigned short h0buf[2][16][136];
    __shared__ __align__(16) unsigned short h1buf[2][16][136];

    if (w < 4) {
        const int r0 = w * 32 + quad * 4;
        const int r1 = r0 + 16;
        short8 a0[2][4];
#pragma unroll
        for (int r = 0; r < 2; ++r) {
            const size_t mrow = (size_t)(w * 32 + r * 16 + n) * 128;
#pragma unroll
            for (int ks = 0; ks < 4; ++ks)
                a0[r][ks] = ld_a_bf16(w_hh0 + mrow + ks * 32 + quad * 8);
        }
        const size_t wegB0 = (size_t)(bbase + n) * 131072 + r0;
        const size_t wegB1 = wegB0 + 16;
        {
            float4 p0 = *(const float4*)(WEg + wegB0);
            float4 p1 = *(const float4*)(WEg + wegB1);
            *(uint2*)&h0buf[0][n][r0] = make_uint2(
                pk_bf16(fast_tanh(p0.x), fast_tanh(p0.y)),
                pk_bf16(fast_tanh(p0.z), fast_tanh(p0.w)));
            *(uint2*)&h0buf[0][n][r1] = make_uint2(
                pk_bf16(fast_tanh(p1.x), fast_tanh(p1.y)),
                pk_bf16(fast_tanh(p1.z), fast_tanh(p1.w)));
        }
        float4 wA0 = *(const float4*)(WEg + wegB0 + 128);
        float4 wA1 = *(const float4*)(WEg + wegB1 + 128);
        float4 wB0 = *(const float4*)(WEg + wegB0 + 256);
        float4 wB1 = *(const float4*)(WEg + wegB1 + 256);
        float4 wC0 = *(const float4*)(WEg + wegB0 + 384);
        float4 wC1 = *(const float4*)(WEg + wegB1 + 384);
        __syncthreads();

        for (int t = 0; t < 1024; ++t) {
            const int p = t & 1;
            if (t < 1023) {
                const unsigned short* h0p = &h0buf[p][n][quad * 8];
                short8 bh[4];
#pragma unroll
                for (int ks = 0; ks < 4; ++ks)
                    bh[ks] = *(const short8*)(h0p + ks * 32);
                f32x4 c0 = (f32x4){wA0.x, wA0.y, wA0.z, wA0.w};
                f32x4 c1 = (f32x4){wA1.x, wA1.y, wA1.z, wA1.w};
#pragma unroll
                for (int ks = 0; ks < 4; ++ks) {
                    c0 = __builtin_amdgcn_mfma_f32_16x16x32_bf16(a0[0][ks], bh[ks], c0, 0,0,0);
                    c1 = __builtin_amdgcn_mfma_f32_16x16x32_bf16(a0[1][ks], bh[ks], c1, 0,0,0);
                }
                wA0 = wB0; wA1 = wB1; wB0 = wC0; wB1 = wC1;
                const size_t tpre = (size_t)((t + 4 < 1024) ? t + 4 : 1023) * 128;
                wC0 = *(const float4*)(WEg + wegB0 + tpre);
                wC1 = *(const float4*)(WEg + wegB1 + tpre);
                *(uint2*)&h0buf[p ^ 1][n][r0] = make_uint2(
                    pk_bf16(fast_tanh(c0[0]), fast_tanh(c0[1])),
                    pk_bf16(fast_tanh(c0[2]), fast_tanh(c0[3])));
                *(uint2*)&h0buf[p ^ 1][n][r1] = make_uint2(
                    pk_bf16(fast_tanh(c1[0]), fast_tanh(c1[1])),
                    pk_bf16(fast_tanh(c1[2]), fast_tanh(c1[3])));
            }
            bar_lds();
        }
    } else {
        const int w2 = w - 4;
        const int r0 = w2 * 32 + quad * 4;
        const int r1 = r0 + 16;
        short8 a1[2][4], a2[2][4];
#pragma unroll
        for (int r = 0; r < 2; ++r) {
            const size_t mrow = (size_t)(w2 * 32 + r * 16 + n) * 128;
#pragma unroll
            for (int ks = 0; ks < 4; ++ks) {
                a1[r][ks] = ld_a_bf16(w_ih1 + mrow + ks * 32 + quad * 8);
                a2[r][ks] = ld_a_bf16(w_hh1 + mrow + ks * 32 + quad * 8);
            }
        }
        f32x4 b1i[2];
#pragma unroll
        for (int r = 0; r < 2; ++r)
#pragma unroll
            for (int j = 0; j < 4; ++j) {
                int row = w2 * 32 + r * 16 + quad * 4 + j;
                b1i[r][j] = b_ih1[row] + b_hh1[row];
            }
        *(uint2*)&h1buf[0][n][r0] = make_uint2(0u, 0u);
        *(uint2*)&h1buf[0][n][r1] = make_uint2(0u, 0u);
        unsigned short* outp0 = outs_bf + (size_t)(bbase + n) * 131072 + r0;
        unsigned short* outp1 = outp0 + 16;
        __syncthreads();

        for (int t = 0; t < 1024; ++t) {
            const int p = t & 1;
            const unsigned short* h0p = &h0buf[p][n][quad * 8];
            const unsigned short* h1p = &h1buf[p][n][quad * 8];
            short8 bh0[4], bh1[4];
#pragma unroll
            for (int ks = 0; ks < 4; ++ks) {
                bh0[ks] = *(const short8*)(h0p + ks * 32);
                bh1[ks] = *(const short8*)(h1p + ks * 32);
            }
            f32x4 c0 = b1i[0], c1 = b1i[1];
            f32x4 d0 = (f32x4){0.f,0.f,0.f,0.f}, d1 = (f32x4){0.f,0.f,0.f,0.f};
#pragma unroll
            for (int ks = 0; ks < 4; ++ks) {
                c0 = __builtin_amdgcn_mfma_f32_16x16x32_bf16(a1[0][ks], bh0[ks], c0, 0,0,0);
                c1 = __builtin_amdgcn_mfma_f32_16x16x32_bf16(a1[1][ks], bh0[ks], c1, 0,0,0);
                d0 = __builtin_amdgcn_mfma_f32_16x16x32_bf16(a2[0][ks], bh1[ks], d0, 0,0,0);
                d1 = __builtin_amdgcn_mfma_f32_16x16x32_bf16(a2[1][ks], bh1[ks], d1, 0,0,0);
            }
            uint2 o0 = make_uint2(
                pk_bf16(fast_tanh(c0[0] + d0[0]), fast_tanh(c0[1] + d0[1])),
                pk_bf16(fast_tanh(c0[2] + d0[2]), fast_tanh(c0[3] + d0[3])));
            uint2 o1 = make_uint2(
                pk_bf16(fast_tanh(c1[0] + d1[0]), fast_tanh(c1[1] + d1[1])),
                pk_bf16(fast_tanh(c1[2] + d1[2]), fast_tanh(c1[3] + d1[3])));
            *(uint2*)&h1buf[p ^ 1][n][r0] = o0;
            *(uint2*)&h1buf[p ^ 1][n][r1] = o1;
            *(uint2*)(outp0 + (size_t)t * 128) = o0;
            *(uint2*)(outp1 + (size_t)t * 128) = o1;
            bar_lds();
        }
    }
}

// ---------------------------------------------------------------------------
// K2: outs [b][t][h] -> outsT [b][h][t]  (LDS tile transpose)
// ---------------------------------------------------------------------------
__global__ __launch_bounds__(256)
void k_transpose(const unsigned short* __restrict__ outs_bf,
                 unsigned short* __restrict__ outsT)
{
    __shared__ unsigned short lt[128][130];
    const int tid = threadIdx.x;
    const int t0  = blockIdx.x * 128;
    const int b   = blockIdx.y;
    const unsigned int* src =
        (const unsigned int*)(outs_bf + ((size_t)b * 1024 + t0) * 128);
    for (int idx = tid; idx < 8192; idx += 256) {
        int tr = idx >> 6, h2 = idx & 63;
        unsigned int v = src[tr * 64 + h2];
        lt[tr][h2 * 2]     = (unsigned short)(v & 0xffffu);
        lt[tr][h2 * 2 + 1] = (unsigned short)(v >> 16);
    }
    __syncthreads();
    unsigned int* dst = (unsigned int*)(outsT + (size_t)b * 128 * 1024);
    for (int idx = tid; idx < 8192; idx += 256) {
        int h = idx >> 6, t2 = idx & 63;
        unsigned int v = (unsigned int)lt[t2 * 2][h] |
                         ((unsigned int)lt[t2 * 2 + 1][h] << 16);
        dst[h * 512 + (t0 >> 1) + t2] = v;
    }
}

// ---------------------------------------------------------------------------
// K4: fused qproj + flash causal attention + FC. One (qt,b) item per block,
// 512 threads (8 waves x 16 q-rows = 128 q). K-tile (from outs) and V^T-tile
// (from outsT) staged in LDS with clean swizzled b128 writes, shared by all
// waves. Math identical to the R9-verified consumer (minus spin/fence).
// ---------------------------------------------------------------------------
__global__ __launch_bounds__(512, 1)
void k_attnfc(const unsigned short* __restrict__ outs_bf,
              const unsigned short* __restrict__ outsT,
              const float* __restrict__ attn_w, const float* __restrict__ attn_b,
              const float* __restrict__ fc_w, const float* __restrict__ fc_b,
              float* __restrict__ out)
{
    __shared__ __align__(16) unsigned char smem[100352];
    unsigned short* lK = (unsigned short*)smem;             // [128][128] swz
    unsigned short* lV = (unsigned short*)(smem + 32768);   // [128][128] swz (V^T)
    unsigned short* lP = (unsigned short*)(smem + 65536);   // [8][16][136]

    const int tid  = threadIdx.x;
    const int w    = tid >> 6;
    const int lane = tid & 63;
    const int quad = lane >> 4;
    const int n    = lane & 15;
    const int qt   = blockIdx.x;
    const int b    = blockIdx.y;
    unsigned short* lPw = lP + w * 2176;
    const float cscale = 0.08838834764831845f;              // 1/sqrt(128)

    const unsigned short* outsB = outs_bf + (size_t)b * 131072;
    const int qrow = qt * 128 + w * 16 + n;                 // this lane's q

    // ---- Phase Q: Q = attn_w @ outs_q + attn_b (per-wave 16 rows) ----
    short8 bo[4];
#pragma unroll
    for (int ks = 0; ks < 4; ++ks)
        bo[ks] = *(const short8*)(outsB + (size_t)qrow * 128 + ks * 32 + quad * 8);
#pragma unroll
    for (int mt = 0; mt < 8; ++mt) {
        short8 aw[4];
#pragma unroll
        for (int ks = 0; ks < 4; ++ks)
            aw[ks] = ld_a_bf16(attn_w + (size_t)(mt * 16 + n) * 128 + ks * 32 + quad * 8);
        f32x4 cq;
#pragma unroll
        for (int r = 0; r < 4; ++r) cq[r] = attn_b[mt * 16 + quad * 4 + r];
#pragma unroll
        for (int ks = 0; ks < 4; ++ks)
            cq = __builtin_amdgcn_mfma_f32_16x16x32_bf16(aw[ks], bo[ks], cq, 0,0,0);
        *(uint2*)&lPw[n * 136 + mt * 16 + quad * 4] =
            make_uint2(pk_bf16(cq[0], cq[1]), pk_bf16(cq[2], cq[3]));
    }
    short8 qf[4];
#pragma unroll
    for (int ks = 0; ks < 4; ++ks)
        qf[ks] = *(const short8*)&lPw[n * 136 + ks * 32 + quad * 8];

    f32x4 accO[8];
#pragma unroll
    for (int dt = 0; dt < 8; ++dt) accO[dt] = (f32x4){0.f, 0.f, 0.f, 0.f};
    float mx = -1e30f, lsum = 0.f;

    for (int kt = 0; kt <= qt; ++kt) {
        __syncthreads();                   // previous iter done with lK/lV
        for (int c = tid; c < 2048; c += 512) {
            int row = c >> 4, k8 = c & 15;
            uint4 vk = *(const uint4*)(outsB + (size_t)(kt * 128 + row) * 128 + k8 * 8);
            *(uint4*)&lK[row * 128 + ((k8 ^ (row & 15)) << 3)] = vk;
            uint4 vv = *(const uint4*)(outsT + ((size_t)b * 128 + row) * 1024 +
                                       kt * 128 + k8 * 8);
            *(uint4*)&lV[row * 128 + ((k8 ^ (row & 15)) << 3)] = vv;
        }
        __syncthreads();
        // ---- S^T = K · Q^T ----
        f32x4 accS[8];
#pragma unroll
        for (int mt = 0; mt < 8; ++mt) {
            short8 af[4];
#pragma unroll
            for (int ks = 0; ks < 4; ++ks) {
                int r = mt * 16 + n;
                af[ks] = *(const short8*)&lK[r * 128 + (((ks * 4 + quad) ^ (r & 15)) << 3)];
            }
            f32x4 s = (f32x4){0.f, 0.f, 0.f, 0.f};
#pragma unroll
            for (int ks = 0; ks < 4; ++ks)
                s = __builtin_amdgcn_mfma_f32_16x16x32_bf16(af[ks], qf[ks], s, 0,0,0);
            accS[mt] = s;
        }
        if (kt == qt) {
            const int ql = w * 16 + n;
#pragma unroll
            for (int mt = 0; mt < 8; ++mt)
#pragma unroll
                for (int jv = 0; jv < 4; ++jv)
                    if (mt * 16 + quad * 4 + jv > ql) accS[mt][jv] = -1e30f;
        }
        // ---- online softmax ----
        float tmax = accS[0][0];
#pragma unroll
        for (int mt = 0; mt < 8; ++mt)
#pragma unroll
            for (int jv = 0; jv < 4; ++jv) tmax = fmaxf(tmax, accS[mt][jv]);
        tmax = fmaxf(tmax, __shfl_xor(tmax, 16));
        tmax = fmaxf(tmax, __shfl_xor(tmax, 32));
        float nm = fmaxf(mx, tmax);
        float alpha = __expf((mx - nm) * cscale);
        float ss = 0.f;
#pragma unroll
        for (int mt = 0; mt < 8; ++mt)
#pragma unroll
            for (int jv = 0; jv < 4; ++jv) {
                float p = __expf((accS[mt][jv] - nm) * cscale);
                accS[mt][jv] = p;
                ss += p;
            }
        ss += __shfl_xor(ss, 16);
        ss += __shfl_xor(ss, 32);
        lsum = lsum * alpha + ss;
        mx = nm;
        // ---- P^T -> wave-private LDS ----
#pragma unroll
        for (int mt = 0; mt < 8; ++mt)
            *(uint2*)&lPw[n * 136 + mt * 16 + quad * 4] = make_uint2(
                pk_bf16(accS[mt][0], accS[mt][1]),
                pk_bf16(accS[mt][2], accS[mt][3]));
#pragma unroll
        for (int dt = 0; dt < 8; ++dt)
#pragma unroll
            for (int jv = 0; jv < 4; ++jv) accO[dt][jv] *= alpha;
        short8 pf[4];
#pragma unroll
        for (int ks = 0; ks < 4; ++ks)
            pf[ks] = *(const short8*)&lPw[n * 136 + ks * 32 + quad * 8];
        // ---- O^T += V^T · P^T ----
#pragma unroll
        for (int dt = 0; dt < 8; ++dt) {
            short8 vf[4];
#pragma unroll
            for (int ks = 0; ks < 4; ++ks) {
                int d = dt * 16 + n;
                vf[ks] = *(const short8*)&lV[d * 128 + (((ks * 4 + quad) ^ (d & 15)) << 3)];
            }
#pragma unroll
            for (int ks = 0; ks < 4; ++ks)
                accO[dt] = __builtin_amdgcn_mfma_f32_16x16x32_bf16(vf[ks], pf[ks], accO[dt], 0,0,0);
        }
    }
    // ---- epilogue: ctx (bf16) -> wave-private LDS ----
    {
        float inv = __builtin_amdgcn_rcpf(lsum);
#pragma unroll
        for (int dt = 0; dt < 8; ++dt)
            *(uint2*)&lPw[n * 136 + dt * 16 + quad * 4] = make_uint2(
                pk_bf16(accO[dt][0] * inv, accO[dt][1] * inv),
                pk_bf16(accO[dt][2] * inv, accO[dt][3] * inv));
    }
    // ---- inline FC: logits = [outs|ctx] @ fc_w.T + fc_b ----
    short8 bC[4];
#pragma unroll
    for (int ks = 0; ks < 4; ++ks)
        bC[ks] = *(const short8*)&lPw[n * 136 + ks * 32 + quad * 8];
#pragma unroll
    for (int mt = 0; mt < 4; ++mt) {
        const int vrow = mt * 16 + n;              // A-operand row (v)
        f32x4 acc;
#pragma unroll
        for (int r = 0; r < 4; ++r) {
            int vv = mt * 16 + quad * 4 + r;
            acc[r] = (vv < 55) ? fc_b[vv] : 0.f;
        }
#pragma unroll
        for (int c = 0; c < 8; ++c) {
            short8 hi, lo;
            if (vrow < 55) {
                ld_fc_hilo(fc_w + (size_t)vrow * 256 + c * 32 + quad * 8, hi, lo);
            } else {
#pragma unroll
                for (int i = 0; i < 8; ++i) { hi[i] = 0; lo[i] = 0; }
            }
            short8 bb = (c < 4) ? bo[c] : bC[c - 4];
            acc = __builtin_amdgcn_mfma_f32_16x16x32_bf16(hi, bb, acc, 0,0,0);
            acc = __builtin_amdgcn_mfma_f32_16x16x32_bf16(lo, bb, acc, 0,0,0);
        }
#pragma unroll
        for (int r = 0; r < 4; ++r) {
            int vv = mt * 16 + quad * 4 + r;
            if (vv < 55)
                out[((size_t)b * 1024 + qrow) * 55 + vv] = acc[r];
        }
    }
}

// ---------------------------------------------------------------------------
extern "C" void kernel_launch(void* const* d_in, const int* in_sizes, int n_in,
                              void* d_out, int out_size, void* d_ws, size_t ws_size,
                              hipStream_t stream)
{
    const int*   x      = (const int*)d_in[0];
    const float* emb    = (const float*)d_in[1];
    const float* w_ih0  = (const float*)d_in[2];
    const float* b_ih0  = (const float*)d_in[3];
    const float* w_hh0  = (const float*)d_in[4];
    const float* b_hh0  = (const float*)d_in[5];
    const float* w_ih1  = (const float*)d_in[6];
    const float* b_ih1  = (const float*)d_in[7];
    const float* w_hh1  = (const float*)d_in[8];
    const float* b_hh1  = (const float*)d_in[9];
    const float* attn_w = (const float*)d_in[10];
    const float* attn_b = (const float*)d_in[11];
    const float* fc_w   = (const float*)d_in[12];
    const float* fc_b   = (const float*)d_in[13];
    float* out = (float*)d_out;

    char* ws = (char*)d_ws;
    unsigned short* outs_bf = (unsigned short*)(ws);                       // 16 MiB
    unsigned short* outsT   = (unsigned short*)(ws + ((size_t)16 << 20));  // 16 MiB
    float*          WEp     = (float*)         (ws + ((size_t)32 << 20));  // 28 KiB
    float*          WEg     = (float*)         (ws + ((size_t)33 << 20));  // 32 MiB

    k_we<<<dim3(55), dim3(128), 0, stream>>>(emb, w_ih0, b_ih0, b_hh0, WEp);
    k_weg<<<dim3(32, 64), dim3(256), 0, stream>>>(x, WEp, WEg);
    k_scan5<<<dim3(4), dim3(512), 0, stream>>>(
        WEg, w_hh0, w_ih1, b_ih1, w_hh1, b_hh1, outs_bf);
    k_transpose<<<dim3(8, 64), dim3(256), 0, stream>>>(outs_bf, outsT);
    k_attnfc<<<dim3(8, 64), dim3(512), 0, stream>>>(
        outs_bf, outsT, attn_w, attn_b, fc_w, fc_b, out);
}